// Round 7
// baseline (148.674 us; speedup 1.0000x reference)
//
#include <hip/hip_runtime.h>
#include <stdint.h>

// AdaptiveTopKSelector: causal-masked row-wise top-512, B*Sq=16384 rows, Sk=4096.
// R7 vs R6 (108.5us, memory-duty-cycle bound at 4.0 TB/s effective):
//   - NT 256 -> 128 (32 elems/thread): 16 blocks/CU (was 8) -> 2x phase
//     diversity to keep HBM busy through each block's compute valleys;
//     2-wave barriers idle less wave-time; 8 back-to-back dwordx4 loads
//     double per-thread MLP.
//   - algorithm unchanged: adaptive-skip 1024-bucket value histogram
//     (E[above]=640, widen-retry for unconditional exactness), suffix scan,
//     unique-crossing bstar election, candidate rank for (Tval,Jthr),
//     counting-sort placement + adaptive region walk, direct global scatter.

#define SK 4096
#define SQ 4096
#define TOPK 512
#define NT 128
#define NB 1024

typedef float vf4 __attribute__((ext_vector_type(4)));

__device__ __forceinline__ uint32_t fkey(float f) {
  uint32_t u = __float_as_uint(f);
  return (u & 0x80000000u) ? ~u : (u | 0x80000000u);
}
__device__ __forceinline__ float finv(uint32_t k) {
  uint32_t u = (k & 0x80000000u) ? (k ^ 0x80000000u) : ~k;
  return __uint_as_float(u);
}
// transposed: thread t's 8 buckets {8t+i} at (i<<7)|t -> lane-consecutive
__device__ __forceinline__ int hIdx(int b) { return ((b & 7) << 7) | (b >> 3); }
__device__ __forceinline__ int bucketOf(float x, float lo, float scale) {
  int b = (int)((x - lo) * scale);
  b = b < 0 ? 0 : b;
  return b > NB - 1 ? NB - 1 : b;
}

__global__ __launch_bounds__(NT) void topk_sel_kernel(
    const float* __restrict__ scores,
    float* __restrict__ mask_out,
    float* __restrict__ idx_out,
    float* __restrict__ sp_out)
{
  __shared__ uint32_t h[NB];                 // counts -> SuffIncl(b+1) -> region fill
  __shared__ unsigned long long sel[TOPK];   // candbuf -> sel entries
  __shared__ uint32_t wsum[2];
  __shared__ uint32_t s_bstar, s_G, s_ncand;
  __shared__ unsigned long long s_CT;

  const int row  = blockIdx.x;
  const int q    = row & (SQ - 1);
  const int n    = q + 1;                    // # real (unmasked) elements
  const int tid  = threadIdx.x;
  const int lane = tid & 63;
  const int w    = tid >> 6;                 // wave 0 or 1
  const size_t rowoff = (size_t)row * SK;

  // ---- issue 8 global loads FIRST (MLP); j = w*2048 + i*256 + lane*4 + c ----
  float xx[32];
  #pragma unroll
  for (int i = 0; i < 8; ++i)
    *reinterpret_cast<float4*>(&xx[4 * i]) =
        *reinterpret_cast<const float4*>(scores + rowoff + w * 2048 + i * 256 + lane * 4);

  // ---- under the load shadow: zero hist, counters, skip level ----
  *reinterpret_cast<uint4*>(&h[tid * 8])     = make_uint4(0u, 0u, 0u, 0u);
  *reinterpret_cast<uint4*>(&h[tid * 8 + 4]) = make_uint4(0u, 0u, 0u, 0u);
  if (tid == 0) s_ncand = 0;
  float lo;
  {
    float p = 640.0f / (float)n;             // P(N(0,1) > lo) target
    lo = (p >= 0.995f) ? -12.0f : 1.41421356f * erfinvf(1.0f - 2.0f * p);
  }

  // ---- causal mask in place (consumes loads) ----
  #pragma unroll
  for (int i = 0; i < 8; ++i) {
    int jb = w * 2048 + i * 256 + lane * 4;
    #pragma unroll
    for (int c = 0; c < 4; ++c)
      if (jb + c > q) xx[4 * i + c] = -1e9f;
  }
  __syncthreads();                           // B1: zeroed hist visible

  // ---- histogram + suffix scan, widen-and-retry (exactness guarantee) ----
  uint32_t cI[8], St = 0, Snext = 0;
  float scale = 1.0f;
  const uint32_t target = (uint32_t)(n < TOPK ? n : TOPK);
  for (int a = 0; ; ++a) {
    if (a) {                                 // retry: widen range, re-zero
      lo = (lo <= -12.0f) ? -3.0e38f : -12.0f;
      *reinterpret_cast<uint4*>(&h[tid * 8])     = make_uint4(0u, 0u, 0u, 0u);
      *reinterpret_cast<uint4*>(&h[tid * 8 + 4]) = make_uint4(0u, 0u, 0u, 0u);
      __syncthreads();
    }
    scale = (float)NB / (6.0f - lo);
    #pragma unroll
    for (int e = 0; e < 32; ++e) {
      float x = xx[e];                       // masked lanes are -1e9 -> skipped
      if (x >= lo) atomicAdd(&h[hIdx(bucketOf(x, lo, scale))], 1u);
    }
    __syncthreads();                         // B2
    uint32_t s = 0;
    #pragma unroll
    for (int i = 0; i < 8; ++i) { cI[i] = h[(i << 7) | tid]; s += cI[i]; }
    uint32_t S = s;
    #pragma unroll
    for (int off = 1; off < 64; off <<= 1) {
      uint32_t vsh = __shfl_down(S, off);
      if (lane + off < 64) S += vsh;
    }
    if (lane == 0) wsum[w] = S;
    __syncthreads();                         // B3
    uint32_t tail = (w == 0) ? wsum[1] : 0u;
    St    = S + tail;                        // # histogrammed in buckets >= 8*tid
    Snext = St - s;                          // ... >= 8*tid+8
    uint32_t H = wsum[0] + wsum[1];
    if (H >= target || a >= 2) break;
  }

  // ---- overwrite hist in place: h[b] := SuffIncl(b+1) = region start ----
  {
    uint32_t r2 = St;
    #pragma unroll
    for (int i = 0; i < 8; ++i) { r2 -= cI[i]; h[(i << 7) | tid] = r2; }
  }

  // ---- merged bstar-find: the unique crossing thread computes it directly ----
  if (q >= TOPK - 1 && St >= TOPK && Snext < TOPK) {
    uint32_t cum = Snext; int bs = -1; uint32_t G = 0;
    #pragma unroll
    for (int i = 7; i >= 0; --i) {
      uint32_t nc = cum + cI[i];
      if (bs < 0 && nc >= TOPK) { bs = 8 * tid + i; G = cum; }
      cum = nc;
    }
    s_bstar = (uint32_t)bs; s_G = G;
  }
  __syncthreads();                           // B4: region starts + bstar visible

  // ---- threshold (Tval, Jthr): 512th-largest (value desc, idx asc) ----
  float Tval; int Jthr;
  if (q >= TOPK - 1) {                       // block-uniform branch
    const uint32_t need  = TOPK - s_G;       // 1..C
    const int      bstar = (int)s_bstar;
    unsigned long long* candbuf = sel;
    #pragma unroll
    for (int e = 0; e < 32; ++e) {
      float x = xx[e];
      if (x >= lo && bucketOf(x, lo, scale) == bstar) {
        int j = w * 2048 + (e >> 2) * 256 + lane * 4 + (e & 3);
        uint32_t p = atomicAdd(&s_ncand, 1u);
        if (p < (uint32_t)TOPK)
          candbuf[p] = ((unsigned long long)fkey(x) << 12)
                     | (unsigned long long)(4095 - j);
      }
    }
    __syncthreads();                         // B5
    const uint32_t C = s_ncand < (uint32_t)TOPK ? s_ncand : (uint32_t)TOPK;
    for (uint32_t cp = tid; cp < C; cp += NT) {
      unsigned long long k = candbuf[cp];
      uint32_t g = 0;
      for (uint32_t u = 0; u < C; ++u) g += (candbuf[u] > k) ? 1u : 0u;
      if (g == need - 1) s_CT = k;           // unique composite at rank `need`
    }
    __syncthreads();                         // B6
    unsigned long long CT = s_CT;
    Tval = finv((uint32_t)(CT >> 12));
    Jthr = 4095 - (int)(CT & 0xFFFull);
  } else {
    // q < 511: top-512 = all n reals + masked j in [q+1, 511] (all == -1e9).
    Tval = -1e9f; Jthr = TOPK - 1;
  }

  // ---- selection + mask write + counting-sort placement ----
  #pragma unroll
  for (int i = 0; i < 8; ++i) {
    int jb = w * 2048 + i * 256 + lane * 4;
    float m[4];
    #pragma unroll
    for (int c = 0; c < 4; ++c) {
      int e = 4 * i + c;
      int j = jb + c;
      float x = xx[e];
      bool pk = (x > Tval) || (x == Tval && j <= Jthr);
      m[c] = pk ? 1.0f : 0.0f;
      if (pk) {
        uint32_t pos; unsigned long long tag;
        if (j <= q) {
          int b = bucketOf(x, lo, scale);
          pos = atomicAdd(&h[hIdx(b)], 1u);  // fill my bucket's region
          tag = (unsigned long long)b;
        } else {
          pos = (uint32_t)j;                 // masked pick: final rank == j
          tag = 0xFFFull;
        }
        if (pos < (uint32_t)TOPK)
          sel[pos] = (tag << 44)
                   | ((unsigned long long)fkey(x) << 12)
                   | (unsigned long long)(4095 - j);
      }
    }
    vf4 mv; mv.x = m[0]; mv.y = m[1]; mv.z = m[2]; mv.w = m[3];
    __builtin_nontemporal_store(mv,
        reinterpret_cast<vf4*>(mask_out + rowoff + jb));
  }
  __syncthreads();                           // B7

  // ---- adaptive region walk + DIRECT global scatter (no LDS round-trip) ----
  const unsigned long long M44 = (1ull << 44) - 1ull;
  float* orow = idx_out + (size_t)row * TOPK;
  #pragma unroll
  for (int o = 0; o < 4; ++o) {
    int p = tid + o * NT;
    unsigned long long e = sel[p];
    uint32_t tg = (uint32_t)(e >> 44);
    float fidx = (float)(4095u - (uint32_t)(e & 0xFFFull));
    int npv = p;
    if (tg != 0xFFFu) {
      unsigned long long myck = e & M44;
      int cb = 0, cg = 0;
      for (int u = p - 1; u >= 0; --u) {     // expected ~2 steps
        unsigned long long eu = sel[u];
        if ((uint32_t)(eu >> 44) != tg) break;
        ++cb; cg += ((eu & M44) > myck) ? 1 : 0;
      }
      for (int u = p + 1; u < TOPK; ++u) {   // expected ~2 steps
        unsigned long long eu = sel[u];
        if ((uint32_t)(eu >> 44) != tg) break;
        cg += ((eu & M44) > myck) ? 1 : 0;
      }
      npv = p - cb + cg;                     // region_start + rank_in_region
    }
    orow[npv] = fidx;                        // plain store: L2 coalesces scatter
  }
  if (row == 0 && tid == 0) sp_out[0] = 0.875f;  // 1 - 512/4096 exactly
}

extern "C" void kernel_launch(void* const* d_in, const int* in_sizes, int n_in,
                              void* d_out, int out_size, void* d_ws, size_t ws_size,
                              hipStream_t stream) {
  const float* scores = (const float*)d_in[0];
  float* out = (float*)d_out;

  const int rows = in_sizes[0] / SK;               // B * Sq = 16384
  const size_t mask_elems = (size_t)rows * SK;
  const size_t idx_elems  = (size_t)rows * TOPK;

  float* mask_out = out;
  float* idx_out  = out + mask_elems;
  float* sp_out   = out + mask_elems + idx_elems;

  hipLaunchKernelGGL(topk_sel_kernel, dim3(rows), dim3(NT), 0, stream,
                     scores, mask_out, idx_out, sp_out);
}

// Round 8
// 103.454 us; speedup vs baseline: 1.4371x; 1.4371x over previous
//
#include <hip/hip_runtime.h>
#include <stdint.h>

// AdaptiveTopKSelector: causal-masked row-wise top-512, B*Sq=16384 rows, Sk=4096.
// R8 = revert to R6 structure (NT=256, 108.5us; R7's NT=128 regressed 37% --
// per-thread serial chains doubled) + epilogue micro-opt: region-walk neighbors
// (+-2) prefetched as 4 independent LDS loads (1 latency instead of 4 dependent
// ~120cy round-trips); dependent walk only beyond +-2 (rare, E[region]~1.3).
//   - adaptive-skip 1024-bucket value histogram (E[above]=640, widen-retry for
//     unconditional exactness), wave shfl suffix scan, unique-crossing bstar
//     election, candidate rank -> (Tval,Jthr), counting-sort placement,
//     region walk for exact jax.lax.top_k order, direct global scatter.
//   - 7 barriers/block; hist zero + erfinvf hidden under load shadow;
//     nontemporal mask stores; plain (L2-coalesced) idx scatter.

#define SK 4096
#define SQ 4096
#define TOPK 512
#define NT 256
#define NB 1024

typedef float vf4 __attribute__((ext_vector_type(4)));

__device__ __forceinline__ uint32_t fkey(float f) {
  uint32_t u = __float_as_uint(f);
  return (u & 0x80000000u) ? ~u : (u | 0x80000000u);
}
__device__ __forceinline__ float finv(uint32_t k) {
  uint32_t u = (k & 0x80000000u) ? (k ^ 0x80000000u) : ~k;
  return __uint_as_float(u);
}
// transposed: thread t's 4 buckets {4t+i} at (i<<8)|t -> lane-consecutive
__device__ __forceinline__ int hIdx(int b) { return ((b & 3) << 8) | (b >> 2); }
__device__ __forceinline__ int bucketOf(float x, float lo, float scale) {
  int b = (int)((x - lo) * scale);
  b = b < 0 ? 0 : b;
  return b > NB - 1 ? NB - 1 : b;
}

__global__ __launch_bounds__(NT) void topk_sel_kernel(
    const float* __restrict__ scores,
    float* __restrict__ mask_out,
    float* __restrict__ idx_out,
    float* __restrict__ sp_out)
{
  __shared__ uint32_t h[NB];                 // counts -> SuffIncl(b+1) -> region fill
  __shared__ unsigned long long sel[TOPK];   // candbuf -> sel entries
  __shared__ uint32_t wsum[4];
  __shared__ uint32_t s_bstar, s_G, s_ncand;
  __shared__ unsigned long long s_CT;

  const int row  = blockIdx.x;
  const int q    = row & (SQ - 1);
  const int n    = q + 1;                    // # real (unmasked) elements
  const int tid  = threadIdx.x;
  const int lane = tid & 63;
  const int w    = tid >> 6;
  const size_t rowoff = (size_t)row * SK;

  // ---- issue global loads FIRST (HBM latency); j = w*1024+i*256+lane*4+c ----
  float xx[16];
  #pragma unroll
  for (int i = 0; i < 4; ++i)
    *reinterpret_cast<float4*>(&xx[4 * i]) =
        *reinterpret_cast<const float4*>(scores + rowoff + w * 1024 + i * 256 + lane * 4);

  // ---- under the load shadow: zero hist, counters, skip level ----
  *reinterpret_cast<uint4*>(&h[tid * 4]) = make_uint4(0u, 0u, 0u, 0u);
  if (tid == 0) s_ncand = 0;
  float lo;
  {
    float p = 640.0f / (float)n;             // P(N(0,1) > lo) target
    lo = (p >= 0.995f) ? -12.0f : 1.41421356f * erfinvf(1.0f - 2.0f * p);
  }

  // ---- causal mask in place (consumes loads) ----
  #pragma unroll
  for (int i = 0; i < 4; ++i) {
    int jb = w * 1024 + i * 256 + lane * 4;
    #pragma unroll
    for (int c = 0; c < 4; ++c)
      if (jb + c > q) xx[4 * i + c] = -1e9f;
  }
  __syncthreads();                           // B1: zeroed hist visible

  // ---- histogram + suffix scan, widen-and-retry (exactness guarantee) ----
  uint32_t cI[4], St = 0, Snext = 0;
  float scale = 1.0f;
  const uint32_t target = (uint32_t)(n < TOPK ? n : TOPK);
  for (int a = 0; ; ++a) {
    if (a) {                                 // retry: widen range, re-zero
      lo = (lo <= -12.0f) ? -3.0e38f : -12.0f;
      *reinterpret_cast<uint4*>(&h[tid * 4]) = make_uint4(0u, 0u, 0u, 0u);
      __syncthreads();
    }
    scale = (float)NB / (6.0f - lo);
    #pragma unroll
    for (int e = 0; e < 16; ++e) {
      float x = xx[e];                       // masked lanes are -1e9 -> skipped
      if (x >= lo) atomicAdd(&h[hIdx(bucketOf(x, lo, scale))], 1u);
    }
    __syncthreads();                         // B2
    uint32_t s = 0;
    #pragma unroll
    for (int i = 0; i < 4; ++i) { cI[i] = h[(i << 8) | tid]; s += cI[i]; }
    uint32_t S = s;
    #pragma unroll
    for (int off = 1; off < 64; off <<= 1) {
      uint32_t vsh = __shfl_down(S, off);
      if (lane + off < 64) S += vsh;
    }
    if (lane == 0) wsum[w] = S;
    __syncthreads();                         // B3
    uint32_t tail = 0;
    #pragma unroll
    for (int w2 = 0; w2 < 4; ++w2) if (w2 > w) tail += wsum[w2];
    St    = S + tail;                        // # histogrammed in buckets >= 4*tid
    Snext = St - s;                          // ... >= 4*tid+4
    uint32_t H = wsum[0] + wsum[1] + wsum[2] + wsum[3];
    if (H >= target || a >= 2) break;
  }

  // ---- overwrite hist in place: h[b] := SuffIncl(b+1) = region start ----
  {
    uint32_t r2 = St;
    #pragma unroll
    for (int i = 0; i < 4; ++i) { r2 -= cI[i]; h[(i << 8) | tid] = r2; }
  }

  // ---- merged bstar-find: the unique crossing thread computes it directly ----
  if (q >= TOPK - 1 && St >= TOPK && Snext < TOPK) {
    uint32_t cum = Snext; int bs = -1; uint32_t G = 0;
    #pragma unroll
    for (int i = 3; i >= 0; --i) {
      uint32_t nc = cum + cI[i];
      if (bs < 0 && nc >= TOPK) { bs = 4 * tid + i; G = cum; }
      cum = nc;
    }
    s_bstar = (uint32_t)bs; s_G = G;
  }
  __syncthreads();                           // B4: region starts + bstar visible

  // ---- threshold (Tval, Jthr): 512th-largest (value desc, idx asc) ----
  float Tval; int Jthr;
  if (q >= TOPK - 1) {                       // block-uniform branch
    const uint32_t need  = TOPK - s_G;       // 1..C
    const int      bstar = (int)s_bstar;
    unsigned long long* candbuf = sel;
    #pragma unroll
    for (int e = 0; e < 16; ++e) {
      float x = xx[e];
      if (x >= lo && bucketOf(x, lo, scale) == bstar) {
        int j = w * 1024 + (e >> 2) * 256 + lane * 4 + (e & 3);
        uint32_t p = atomicAdd(&s_ncand, 1u);
        if (p < (uint32_t)TOPK)
          candbuf[p] = ((unsigned long long)fkey(x) << 12)
                     | (unsigned long long)(4095 - j);
      }
    }
    __syncthreads();                         // B5
    const uint32_t C = s_ncand < (uint32_t)TOPK ? s_ncand : (uint32_t)TOPK;
    for (uint32_t cp = tid; cp < C; cp += NT) {
      unsigned long long k = candbuf[cp];
      uint32_t g = 0;
      for (uint32_t u = 0; u < C; ++u) g += (candbuf[u] > k) ? 1u : 0u;
      if (g == need - 1) s_CT = k;           // unique composite at rank `need`
    }
    __syncthreads();                         // B6
    unsigned long long CT = s_CT;
    Tval = finv((uint32_t)(CT >> 12));
    Jthr = 4095 - (int)(CT & 0xFFFull);
  } else {
    // q < 511: top-512 = all n reals + masked j in [q+1, 511] (all == -1e9).
    Tval = -1e9f; Jthr = TOPK - 1;
  }

  // ---- selection + mask write + counting-sort placement ----
  #pragma unroll
  for (int i = 0; i < 4; ++i) {
    int jb = w * 1024 + i * 256 + lane * 4;
    float m[4];
    #pragma unroll
    for (int c = 0; c < 4; ++c) {
      int e = 4 * i + c;
      int j = jb + c;
      float x = xx[e];
      bool pk = (x > Tval) || (x == Tval && j <= Jthr);
      m[c] = pk ? 1.0f : 0.0f;
      if (pk) {
        uint32_t pos; unsigned long long tag;
        if (j <= q) {
          int b = bucketOf(x, lo, scale);
          pos = atomicAdd(&h[hIdx(b)], 1u);  // fill my bucket's region
          tag = (unsigned long long)b;
        } else {
          pos = (uint32_t)j;                 // masked pick: final rank == j
          tag = 0xFFFull;
        }
        if (pos < (uint32_t)TOPK)
          sel[pos] = (tag << 44)
                   | ((unsigned long long)fkey(x) << 12)
                   | (unsigned long long)(4095 - j);
      }
    }
    vf4 mv; mv.x = m[0]; mv.y = m[1]; mv.z = m[2]; mv.w = m[3];
    __builtin_nontemporal_store(mv,
        reinterpret_cast<vf4*>(mask_out + rowoff + jb));
  }
  __syncthreads();                           // B7

  // ---- region walk with +-2 neighbor prefetch + direct global scatter ----
  const unsigned long long M44 = (1ull << 44) - 1ull;
  float* orow = idx_out + (size_t)row * TOPK;
  #pragma unroll
  for (int o = 0; o < 2; ++o) {
    int p = tid + o * NT;
    unsigned long long e = sel[p];
    // prefetch +-2 neighbors: 4 INDEPENDENT LDS loads (one latency, not four)
    unsigned long long eL0 = (p >= 1)        ? sel[p - 1] : 0ull;
    unsigned long long eL1 = (p >= 2)        ? sel[p - 2] : 0ull;
    unsigned long long eH0 = (p + 1 < TOPK)  ? sel[p + 1] : 0ull;
    unsigned long long eH1 = (p + 2 < TOPK)  ? sel[p + 2] : 0ull;
    uint32_t tg = (uint32_t)(e >> 44);
    float fidx = (float)(4095u - (uint32_t)(e & 0xFFFull));
    int npv = p;
    if (tg != 0xFFFu) {
      unsigned long long myck = e & M44;
      int cb = 0, cg = 0;
      // left side
      if (p >= 1 && (uint32_t)(eL0 >> 44) == tg) {
        ++cb; cg += ((eL0 & M44) > myck) ? 1 : 0;
        if (p >= 2 && (uint32_t)(eL1 >> 44) == tg) {
          ++cb; cg += ((eL1 & M44) > myck) ? 1 : 0;
          for (int u = p - 3; u >= 0; --u) {         // rare continuation
            unsigned long long eu = sel[u];
            if ((uint32_t)(eu >> 44) != tg) break;
            ++cb; cg += ((eu & M44) > myck) ? 1 : 0;
          }
        }
      }
      // right side
      if (p + 1 < TOPK && (uint32_t)(eH0 >> 44) == tg) {
        cg += ((eH0 & M44) > myck) ? 1 : 0;
        if (p + 2 < TOPK && (uint32_t)(eH1 >> 44) == tg) {
          cg += ((eH1 & M44) > myck) ? 1 : 0;
          for (int u = p + 3; u < TOPK; ++u) {       // rare continuation
            unsigned long long eu = sel[u];
            if ((uint32_t)(eu >> 44) != tg) break;
            cg += ((eu & M44) > myck) ? 1 : 0;
          }
        }
      }
      npv = p - cb + cg;                     // region_start + rank_in_region
    }
    orow[npv] = fidx;                        // plain store: L2 coalesces scatter
  }
  if (row == 0 && tid == 0) sp_out[0] = 0.875f;  // 1 - 512/4096 exactly
}

extern "C" void kernel_launch(void* const* d_in, const int* in_sizes, int n_in,
                              void* d_out, int out_size, void* d_ws, size_t ws_size,
                              hipStream_t stream) {
  const float* scores = (const float*)d_in[0];
  float* out = (float*)d_out;

  const int rows = in_sizes[0] / SK;               // B * Sq = 16384
  const size_t mask_elems = (size_t)rows * SK;
  const size_t idx_elems  = (size_t)rows * TOPK;

  float* mask_out = out;
  float* idx_out  = out + mask_elems;
  float* sp_out   = out + mask_elems + idx_elems;

  hipLaunchKernelGGL(topk_sel_kernel, dim3(rows), dim3(NT), 0, stream,
                     scores, mask_out, idx_out, sp_out);
}